// Round 7
// baseline (206.389 us; speedup 1.0000x reference)
//
#include <hip/hip_runtime.h>

namespace {

constexpr int BATCH = 256;
constexpr int DCAPS = 10;
constexpr int PCAPS = 1152;
constexpr int ODIM  = 16;
constexpr int IDIM  = 8;
constexpr float EPS_ = 1e-7f;

constexpr int BT  = 64;               // b's per block (lane = b)
constexpr int NBB = BATCH / BT;       // 4
constexpr int SDO = BATCH * DCAPS * ODIM;  // 40960

// Routing pass. Lane = b, wave = d-pair (5 waves), PPBt p's per block.
// R6 lesson: W through the scalar path serializes (SGPR file ~100 regs can't
// buffer 256 floats/p-iter -> s_load/waitcnt chains vs 200-300cy L2 latency,
// VALUBusy 22%). Fix: stage W tile in LDS (30KB @PPB=6) with one cooperative
// coalesced load per block; p-loop reads wave-uniform W via ds_read_b128
// (broadcast, conflict-free, ~120cy, deep ILP into VGPRs).
// launch_bounds (320,4): VGPR cap 128 -> allows 16 waves/CU (3 blocks x 5
// waves). R2 lesson: if WRITE_SIZE balloons past ~32MB, it's spilling.
template <int NV, int PPBt>
__global__ __launch_bounds__(320, 4)
void route_kernel(const float* __restrict__ x, const float* __restrict__ W,
                  const float* __restrict__ v0, const float* __restrict__ v1,
                  float* __restrict__ part)
{
    constexpr int NPBLK = PCAPS / PPBt;
    constexpr int XSTR  = PPBt * IDIM + 1;   // odd stride: b32 reads conflict-free
    constexpr int WT4   = PPBt * DCAPS * ODIM * IDIM / 4;  // W tile in float4

    const int tid  = threadIdx.x;
    const int lane = tid & 63;
    const int wid  = __builtin_amdgcn_readfirstlane(tid >> 6);
    const int d0   = 2 * wid;
    const int pBlk = blockIdx.x % NPBLK;     // pBlk fastest: all bBlk copies of a
    const int bBlk = blockIdx.x / NPBLK;     // pBlk land on the same XCD (192%8==0)
    const int b    = bBlk * BT + lane;
    const int p0   = pBlk * PPBt;

    __shared__ float wlds[PPBt * DCAPS * ODIM * IDIM];  // 30KB @PPB6
    __shared__ float xs[BT][XSTR];                      // 12.5KB @PPB6
    __shared__ float lx[DCAPS][BT];                     // 2.5KB

    // ---- stage W[d, p0:p0+PPBt, :, :] into LDS; dest index == k (linear),
    //      source runs are 32 consecutive float4 per (d,pp) slab -> coalesced
    float4* wl4 = reinterpret_cast<float4*>(wlds);
    const float4* W4 = reinterpret_cast<const float4*>(W);
    for (int k = tid; k < WT4; k += 320) {
        const int d   = k / (PPBt * 32);
        const int rem = k - d * (PPBt * 32);
        const int pp  = rem >> 5;
        const int q   = rem & 31;
        wl4[k] = W4[((size_t)d * PCAPS + p0 + pp) * 32 + q];
    }
    // ---- stage x[bTile, p0:p0+PPBt, :] into LDS ----
    const float4* X4 = reinterpret_cast<const float4*>(x);
    for (int k = tid; k < BT * PPBt * 2; k += 320) {
        const int bl = k / (PPBt * 2);
        const int j  = k - bl * (PPBt * 2);
        const int pp = j >> 1;
        const int h  = j & 1;
        const float4 t = X4[((size_t)(bBlk * BT + bl) * PCAPS + p0 + pp) * 2 + h];
        float* dst = &xs[bl][pp * IDIM + h * 4];
        dst[0] = t.x; dst[1] = t.y; dst[2] = t.z; dst[3] = t.w;
    }
    __syncthreads();

    // ---- preload v[b, d0:d0+2, :] (uv(v0)+uv(v1) = uv(v0+v1)) ----
    float vr[2][ODIM];
    if constexpr (NV >= 1) {
#pragma unroll
        for (int dd = 0; dd < 2; ++dd) {
            const float4* vp = reinterpret_cast<const float4*>(
                v0 + ((size_t)b * DCAPS + d0 + dd) * ODIM);
#pragma unroll
            for (int q = 0; q < 4; ++q) {
                float4 t = vp[q];
                if constexpr (NV == 2) {
                    const float4 u = reinterpret_cast<const float4*>(
                        v1 + ((size_t)b * DCAPS + d0 + dd) * ODIM)[q];
                    t.x += u.x; t.y += u.y; t.z += u.z; t.w += u.w;
                }
                vr[dd][q * 4 + 0] = t.x; vr[dd][q * 4 + 1] = t.y;
                vr[dd][q * 4 + 2] = t.z; vr[dd][q * 4 + 3] = t.w;
            }
        }
    }

    float s_acc[2][ODIM];
#pragma unroll
    for (int dd = 0; dd < 2; ++dd)
#pragma unroll
        for (int o = 0; o < ODIM; ++o) s_acc[dd][o] = 0.f;

    for (int pp = 0; pp < PPBt; ++pp) {
        float xr[IDIM];
#pragma unroll
        for (int i = 0; i < IDIM; ++i) xr[i] = xs[lane][pp * IDIM + i];

        // u_hat from LDS-W (wave-uniform addr -> broadcast)
        float uh[2][ODIM];
#pragma unroll
        for (int dd = 0; dd < 2; ++dd) {
            const float4* wv = reinterpret_cast<const float4*>(wlds)
                               + ((size_t)(d0 + dd) * PPBt + pp) * 32;
#pragma unroll
            for (int o = 0; o < ODIM; ++o) {
                const float4 wa = wv[o * 2 + 0];
                const float4 wb = wv[o * 2 + 1];
                float acc;
                acc = wa.x * xr[0];
                acc = fmaf(wa.y, xr[1], acc);
                acc = fmaf(wa.z, xr[2], acc);
                acc = fmaf(wa.w, xr[3], acc);
                acc = fmaf(wb.x, xr[4], acc);
                acc = fmaf(wb.y, xr[5], acc);
                acc = fmaf(wb.z, xr[6], acc);
                acc = fmaf(wb.w, xr[7], acc);
                uh[dd][o] = acc;
            }
        }

        if constexpr (NV == 0) {
#pragma unroll
            for (int dd = 0; dd < 2; ++dd)
#pragma unroll
                for (int o = 0; o < ODIM; ++o)
                    s_acc[dd][o] = fmaf(0.1f, uh[dd][o], s_acc[dd][o]);
        } else {
            float l2[2];
#pragma unroll
            for (int dd = 0; dd < 2; ++dd) {
                float t = uh[dd][0] * vr[dd][0];
#pragma unroll
                for (int o = 1; o < ODIM; ++o) t = fmaf(uh[dd][o], vr[dd][o], t);
                l2[dd] = t;
            }
            lx[d0 + 0][lane] = l2[0];
            lx[d0 + 1][lane] = l2[1];
            __syncthreads();
            float lv[DCAPS];
#pragma unroll
            for (int d = 0; d < DCAPS; ++d) lv[d] = lx[d][lane];
            __syncthreads();
            float mx = lv[0];
#pragma unroll
            for (int d = 1; d < DCAPS; ++d) mx = fmaxf(mx, lv[d]);
            float den = 0.f;
#pragma unroll
            for (int d = 0; d < DCAPS; ++d) den += __expf(lv[d] - mx);
            const float inv = 1.0f / den;
#pragma unroll
            for (int dd = 0; dd < 2; ++dd) {
                const float c = __expf(l2[dd] - mx) * inv;
#pragma unroll
                for (int o = 0; o < ODIM; ++o)
                    s_acc[dd][o] = fmaf(c, uh[dd][o], s_acc[dd][o]);
            }
        }
    }

    // partial store: part[pBlk][bBlk][d][lane][o], coalesced dwordx4
#pragma unroll
    for (int dd = 0; dd < 2; ++dd) {
        float* dst = part + ((((size_t)pBlk * NBB + bBlk) * DCAPS + d0 + dd) * BT
                             + lane) * ODIM;
#pragma unroll
        for (int q = 0; q < 4; ++q) {
            float4 t;
            t.x = s_acc[dd][q * 4 + 0]; t.y = s_acc[dd][q * 4 + 1];
            t.z = s_acc[dd][q * 4 + 2]; t.w = s_acc[dd][q * 4 + 3];
            reinterpret_cast<float4*>(dst)[q] = t;
        }
    }
}

// Sum NP chunk-partials then squash. Parallel version (R6 squash was 80
// blocks / 20K threads, latency-bound ~14us): 320 blocks x 256 threads,
// thread = (unit u, chunk-group cg, float4-quarter q); 64B coalesced reads.
template <int NP>
__global__ __launch_bounds__(256)
void squash_kernel(const float* __restrict__ part, float* __restrict__ out)
{
    constexpr int CPC = NP / 8;
    const int tid = threadIdx.x;
    const int u   = tid >> 5;            // 0..7 unit within block
    const int l   = tid & 31;
    const int cg  = l >> 2;              // 0..7 chunk group
    const int q   = l & 3;               // float4 quarter
    const int gu  = blockIdx.x * 8 + u;  // global unit = b*DCAPS + d
    const int b   = gu / DCAPS;
    const int d   = gu - b * DCAPS;
    const int bb  = b >> 6;
    const int bl  = b & 63;

    float4 acc = make_float4(0, 0, 0, 0);
    for (int k = 0; k < CPC; ++k) {
        const int c = cg * CPC + k;
        const float4 p4 = reinterpret_cast<const float4*>(
            part + ((((size_t)c * NBB + bb) * DCAPS + d) * BT + bl) * ODIM)[q];
        acc.x += p4.x; acc.y += p4.y; acc.z += p4.z; acc.w += p4.w;
    }

    __shared__ float4 sred[8][8][4];
    __shared__ float4 sfin[8][4];
    __shared__ float  nrm[8][4];
    __shared__ float  sscale[8];
    sred[u][cg][q] = acc;
    __syncthreads();

    if (cg == 0) {
        float4 s = sred[u][0][q];
#pragma unroll
        for (int c2 = 1; c2 < 8; ++c2) {
            const float4 t = sred[u][c2][q];
            s.x += t.x; s.y += t.y; s.z += t.z; s.w += t.w;
        }
        sfin[u][q] = s;
        nrm[u][q]  = s.x * s.x + s.y * s.y + s.z * s.z + s.w * s.w;
    }
    __syncthreads();
    if (l == 0) {
        const float sq = nrm[u][0] + nrm[u][1] + nrm[u][2] + nrm[u][3];
        sscale[u] = (sq / (1.0f + sq)) / sqrtf(sq + EPS_);
    }
    __syncthreads();
    if (cg == 0) {
        float4 s = sfin[u][q];
        const float sc = sscale[u];
        s.x *= sc; s.y *= sc; s.z *= sc; s.w *= sc;
        reinterpret_cast<float4*>(out)[(size_t)gu * 4 + q] = s;
    }
}

template <int PPBt>
void run_all(const float* x, const float* W, float* v0, float* v1, float* part,
             float* out, hipStream_t stream)
{
    constexpr int NPBLK = PCAPS / PPBt;
    const dim3 rblk(320);
    const dim3 rgrid(NPBLK * NBB);
    const dim3 sblk(256);
    const dim3 sgrid(BATCH * DCAPS / 8);   // 320

    route_kernel<0, PPBt><<<rgrid, rblk, 0, stream>>>(x, W, nullptr, nullptr, part);
    squash_kernel<NPBLK><<<sgrid, sblk, 0, stream>>>(part, v0);

    route_kernel<1, PPBt><<<rgrid, rblk, 0, stream>>>(x, W, v0, nullptr, part);
    squash_kernel<NPBLK><<<sgrid, sblk, 0, stream>>>(part, v1);

    route_kernel<2, PPBt><<<rgrid, rblk, 0, stream>>>(x, W, v0, v1, part);
    squash_kernel<NPBLK><<<sgrid, sblk, 0, stream>>>(part, out);
}

} // namespace

extern "C" void kernel_launch(void* const* d_in, const int* in_sizes, int n_in,
                              void* d_out, int out_size, void* d_ws, size_t ws_size,
                              hipStream_t stream)
{
    const float* x = (const float*)d_in[0];   // [256, 1152, 8]
    const float* W = (const float*)d_in[1];   // [1, 10, 1152, 16, 8]
    float* out = (float*)d_out;               // [256, 10, 16]

    float* v0   = (float*)d_ws;
    float* v1   = v0 + SDO;
    float* part = v1 + SDO;

    const size_t need6 = ((size_t)2 + 192) * SDO * sizeof(float);  // 31.8 MB
    if (ws_size >= need6) {
        // PPB=6: LDS 45.8KB -> 3 blocks/CU, grid 768
        run_all<6>(x, W, v0, v1, part, out, stream);
    } else {
        // PPB=9: LDS 67KB -> 2 blocks/CU, grid 512 (21.3MB partials, R5-proven)
        run_all<9>(x, W, v0, v1, part, out, stream);
    }
}

// Round 8
// 202.713 us; speedup vs baseline: 1.0181x; 1.0181x over previous
//
#include <hip/hip_runtime.h>

namespace {

constexpr int BATCH = 256;
constexpr int DCAPS = 10;
constexpr int PCAPS = 1152;
constexpr int ODIM  = 16;
constexpr int IDIM  = 8;
constexpr float EPS_ = 1e-7f;

constexpr int NPBLK = 128;            // p-blocks
constexpr int PPB   = PCAPS / NPBLK;  // 9 p's per block
constexpr int BPG   = 2;              // b's unrolled per 16-lane group
constexpr int GPB   = 16;             // groups per 256-thread block
constexpr int BT    = GPB * BPG;      // 32 b's per block
constexpr int NBB   = BATCH / BT;     // 8
constexpr int SDO   = BATCH * DCAPS * ODIM;  // 40960
constexpr float LOG2E = 1.44269504088896f;

// Sum across the 16-lane row via DPP rotate-reduce (VALU pipe, not LDS).
// R5 used __shfl_xor (ds_bpermute = LDS pipe); with 160 reductions per
// p-iter that contends with nothing here -- DPP is free concurrency.
__device__ __forceinline__ float rsum16(float v)
{
    v += __int_as_float(__builtin_amdgcn_update_dpp(
        0, __float_as_int(v), 0x121, 0xF, 0xF, true));   // row_ror:1
    v += __int_as_float(__builtin_amdgcn_update_dpp(
        0, __float_as_int(v), 0x122, 0xF, 0xF, true));   // row_ror:2
    v += __int_as_float(__builtin_amdgcn_update_dpp(
        0, __float_as_int(v), 0x124, 0xF, 0xF, true));   // row_ror:4
    v += __int_as_float(__builtin_amdgcn_update_dpp(
        0, __float_as_int(v), 0x128, 0xF, 0xF, true));   // row_ror:8
    return v;                                            // all 16 lanes = total
}

__device__ __forceinline__ float dot8(const float4& wa, const float4& wb,
                                      const float4& xa, const float4& xb)
{
    float acc = wa.x * xa.x;
    acc = fmaf(wa.y, xa.y, acc);
    acc = fmaf(wa.z, xa.z, acc);
    acc = fmaf(wa.w, xa.w, acc);
    acc = fmaf(wb.x, xb.x, acc);
    acc = fmaf(wb.y, xb.y, acc);
    acc = fmaf(wb.z, xb.z, acc);
    acc = fmaf(wb.w, xb.w, acc);
    return acc;
}

// Routing pass. Structure = R5 (lane = o, per-lane-DISTINCT W addresses --
// every L1 byte written back is useful; R6/R7 lesson: any broadcast W path
// wastes 32-64x of the operand return bandwidth) + 2-b unroll (halves W
// load instrs per useful FMA, R5's limiter) + DPP reductions + exp2 softmax
// without max-subtraction (logits |l| < ~0.5 since W ~ 0.01: no overflow).
// Pure-register kernel: no LDS, no barriers, no atomics.
// launch_bounds (256,4): VGPR cap 128 (live ~110). R2 lesson: a tighter
// bound spills (WRITE_SIZE balloons); watch WRITE_SIZE ~ 20.5 MB = partials.
template <int NV>
__global__ __launch_bounds__(256, 4)
void route_kernel(const float* __restrict__ x, const float* __restrict__ W,
                  const float* __restrict__ v0, const float* __restrict__ v1,
                  float* __restrict__ part)
{
    const int tid  = threadIdx.x;
    const int g    = tid >> 4;            // 16-lane group
    const int o    = tid & 15;            // output dim
    const int pBlk = blockIdx.x % NPBLK;  // pBlk fastest -> spread over XCDs
    const int bBlk = blockIdx.x / NPBLK;
    const int b0   = bBlk * BT + g * BPG;
    const int p0   = pBlk * PPB;

    // preload v (sum of provided v's: uv(v0)+uv(v1) = uv(v0+v1)), pre-scaled
    // by log2(e) so softmax uses exp2 directly.
    float vr[BPG][DCAPS];
    if constexpr (NV >= 1) {
#pragma unroll
        for (int bb = 0; bb < BPG; ++bb)
#pragma unroll
            for (int d = 0; d < DCAPS; ++d) {
                float t = v0[((size_t)(b0 + bb) * DCAPS + d) * ODIM + o];
                if constexpr (NV == 2)
                    t += v1[((size_t)(b0 + bb) * DCAPS + d) * ODIM + o];
                vr[bb][d] = t * LOG2E;
            }
    }

    float s_acc[BPG][DCAPS];
#pragma unroll
    for (int bb = 0; bb < BPG; ++bb)
#pragma unroll
        for (int d = 0; d < DCAPS; ++d) s_acc[bb][d] = 0.f;

    for (int pp = 0; pp < PPB; ++pp) {
        const int p = p0 + pp;

        // x for both b's: group-uniform 16B loads (L1 broadcast)
        float4 xa[BPG], xb[BPG];
#pragma unroll
        for (int bb = 0; bb < BPG; ++bb) {
            const float4* xp = reinterpret_cast<const float4*>(
                x + ((size_t)(b0 + bb) * PCAPS + p) * IDIM);
            xa[bb] = xp[0];
            xb[bb] = xp[1];
        }

        // u_hat: one W fragment load serves BPG b's
        float uh[BPG][DCAPS];
#pragma unroll
        for (int d = 0; d < DCAPS; ++d) {
            const float4* wp = reinterpret_cast<const float4*>(
                W + (((size_t)d * PCAPS + p) * ODIM + o) * IDIM);
            const float4 wa = wp[0];
            const float4 wb = wp[1];
#pragma unroll
            for (int bb = 0; bb < BPG; ++bb)
                uh[bb][d] = dot8(wa, wb, xa[bb], xb[bb]);
        }

        if constexpr (NV == 0) {
#pragma unroll
            for (int bb = 0; bb < BPG; ++bb)
#pragma unroll
                for (int d = 0; d < DCAPS; ++d)
                    s_acc[bb][d] = fmaf(0.1f, uh[bb][d], s_acc[bb][d]);
        } else {
            // softmax over d (no max-subtraction: logits are O(0.1))
            float e[BPG][DCAPS];
            float den[BPG];
#pragma unroll
            for (int bb = 0; bb < BPG; ++bb) den[bb] = 0.f;
#pragma unroll
            for (int bb = 0; bb < BPG; ++bb)
#pragma unroll
                for (int d = 0; d < DCAPS; ++d) {
                    const float l = rsum16(uh[bb][d] * vr[bb][d]);
                    const float t = exp2f(l);
                    e[bb][d] = t;
                    den[bb] += t;
                }
#pragma unroll
            for (int bb = 0; bb < BPG; ++bb) {
                const float inv = 1.0f / den[bb];
#pragma unroll
                for (int d = 0; d < DCAPS; ++d)
                    s_acc[bb][d] = fmaf(e[bb][d] * inv, uh[bb][d], s_acc[bb][d]);
            }
        }
    }

    // partial store: part[pBlk][b][d][o] -- 16 lanes write contiguous 64B
#pragma unroll
    for (int bb = 0; bb < BPG; ++bb)
#pragma unroll
        for (int d = 0; d < DCAPS; ++d)
            part[((size_t)pBlk * BATCH + (b0 + bb)) * (DCAPS * ODIM)
                 + d * ODIM + o] = s_acc[bb][d];
}

// Sum NP chunk-partials then squash. 320 blocks x 256 threads:
// thread = (unit u, chunk-group cg, float4-quarter q); 64B coalesced reads.
template <int NP>
__global__ __launch_bounds__(256)
void squash_kernel(const float* __restrict__ part, float* __restrict__ out)
{
    constexpr int CPC = NP / 8;
    const int tid = threadIdx.x;
    const int u   = tid >> 5;            // 0..7 unit within block
    const int l   = tid & 31;
    const int cg  = l >> 2;              // 0..7 chunk group
    const int q   = l & 3;               // float4 quarter
    const int gu  = blockIdx.x * 8 + u;  // global unit = b*DCAPS + d

    float4 acc = make_float4(0, 0, 0, 0);
    for (int k = 0; k < CPC; ++k) {
        const int c = cg * CPC + k;
        const float4 p4 = reinterpret_cast<const float4*>(
            part + (size_t)c * SDO + (size_t)gu * ODIM)[q];
        acc.x += p4.x; acc.y += p4.y; acc.z += p4.z; acc.w += p4.w;
    }

    __shared__ float4 sred[8][8][4];
    __shared__ float4 sfin[8][4];
    __shared__ float  nrm[8][4];
    __shared__ float  sscale[8];
    sred[u][cg][q] = acc;
    __syncthreads();

    if (cg == 0) {
        float4 s = sred[u][0][q];
#pragma unroll
        for (int c2 = 1; c2 < 8; ++c2) {
            const float4 t = sred[u][c2][q];
            s.x += t.x; s.y += t.y; s.z += t.z; s.w += t.w;
        }
        sfin[u][q] = s;
        nrm[u][q]  = s.x * s.x + s.y * s.y + s.z * s.z + s.w * s.w;
    }
    __syncthreads();
    if (l == 0) {
        const float sq = nrm[u][0] + nrm[u][1] + nrm[u][2] + nrm[u][3];
        sscale[u] = (sq / (1.0f + sq)) / sqrtf(sq + EPS_);
    }
    __syncthreads();
    if (cg == 0) {
        float4 s = sfin[u][q];
        const float sc = sscale[u];
        s.x *= sc; s.y *= sc; s.z *= sc; s.w *= sc;
        reinterpret_cast<float4*>(out)[(size_t)gu * 4 + q] = s;
    }
}

} // namespace

extern "C" void kernel_launch(void* const* d_in, const int* in_sizes, int n_in,
                              void* d_out, int out_size, void* d_ws, size_t ws_size,
                              hipStream_t stream)
{
    const float* x = (const float*)d_in[0];   // [256, 1152, 8]
    const float* W = (const float*)d_in[1];   // [1, 10, 1152, 16, 8]
    float* out = (float*)d_out;               // [256, 10, 16]

    float* v0   = (float*)d_ws;
    float* v1   = v0 + SDO;
    float* part = v1 + SDO;                   // NPBLK * SDO floats (21 MB, proven fit)

    const dim3 rblk(256);
    const dim3 rgrid(NPBLK * NBB);            // 1024
    const dim3 sblk(256);
    const dim3 sgrid(BATCH * DCAPS / 8);      // 320

    // pass 0: c uniform 0.1 -> s0 -> v0
    route_kernel<0><<<rgrid, rblk, 0, stream>>>(x, W, nullptr, nullptr, part);
    squash_kernel<NPBLK><<<sgrid, sblk, 0, stream>>>(part, v0);

    // pass 1: logits = uv(v0) -> s1 -> v1
    route_kernel<1><<<rgrid, rblk, 0, stream>>>(x, W, v0, nullptr, part);
    squash_kernel<NPBLK><<<sgrid, sblk, 0, stream>>>(part, v1);

    // pass 2: logits = uv(v0)+uv(v1) = uv(v0+v1) -> s2 -> out
    route_kernel<2><<<rgrid, rblk, 0, stream>>>(x, W, v0, v1, part);
    squash_kernel<NPBLK><<<sgrid, sblk, 0, stream>>>(part, out);
}